// Round 1
// baseline (25.374 us; speedup 1.0000x reference)
//
#include <hip/hip_runtime.h>

// StaticSceneFeatureExtractorGrid — fully fused single kernel.
// Phase 1: per-block LDS histogram (4 peds/block, 64 cells each).
// Phase 2: one wave per ped: attention + softmax + gated awe + LSTM cell.

constexpr int CELLS = 64;   // 8x8 grid
constexpr int HD    = 64;   // H_DIM
constexpr int AD    = 32;   // ATT_DIM
constexpr int PPB   = 4;    // peds per block
constexpr int BLK   = 256;  // threads per block (4 waves)

__global__ __launch_bounds__(BLK) void fused_ssfe_kernel(
    const float* __restrict__ scene,     // [npts,2]
    const float* __restrict__ end_pos,   // [nped,2]
    const float* __restrict__ disp_pos,  // [nped,2]
    const float* __restrict__ h_in,      // [nped,64]
    const float* __restrict__ W_enc,     // [1,32]
    const float* __restrict__ b_enc,     // [32]
    const float* __restrict__ W_dec,     // [64,32]
    const float* __restrict__ b_dec,     // [32]
    const float* __restrict__ W_full,    // [32,1]
    const float* __restrict__ b_full,    // [1]
    const float* __restrict__ W_fbeta,   // [64,1]
    const float* __restrict__ b_fbeta,   // [1]
    const float* __restrict__ W_emb,     // [4,4]
    const float* __restrict__ b_emb,     // [4]
    const float* __restrict__ W_ih,      // [5,256]
    const float* __restrict__ b_ih,      // [256]
    const float* __restrict__ W_hh,      // [64,256]
    const float* __restrict__ b_hh,      // [256]
    float* __restrict__ out,             // [nped,64]
    int nped, int npts)
{
    __shared__ unsigned hist[PPB][CELLS];
    __shared__ float    h_s[PPB][HD];
    __shared__ float    att2_s[PPB][AD];

    const int tid  = threadIdx.x;
    const int ped0 = blockIdx.x * PPB;

    // zero histogram (PPB*CELLS == BLK)
    ((unsigned*)hist)[tid] = 0u;

    // stage h into LDS: tid -> (ped p, element k)
    {
        int p = tid >> 6, k = tid & 63;
        int ped = ped0 + p;
        h_s[p][k] = (ped < nped) ? h_in[ped * HD + k] : 0.f;
    }

    // pedestrian boxes in registers (dummy box for tail peds -> always outside)
    float px[PPB], py[PPB];
    #pragma unroll
    for (int p = 0; p < PPB; ++p) {
        int ped = ped0 + p;
        if (ped < nped) { px[p] = end_pos[ped * 2]; py[p] = end_pos[ped * 2 + 1]; }
        else            { px[p] = 1e30f;            py[p] = 1e30f; }
    }
    __syncthreads();

    // ---- Phase 1: histogram -------------------------------------------------
    const float2* sc2 = reinterpret_cast<const float2*>(scene);
    for (int i = tid; i < npts; i += BLK) {
        float2 s = sc2[i];
        #pragma unroll
        for (int p = 0; p < PPB; ++p) {
            // replicate JAX bit-exactly: tlx=px-1, tly=py+1, brx=px+1, bry=py-1
            float tlx = px[p] - 1.0f, tly = py[p] + 1.0f;
            float brx = px[p] + 1.0f, bry = py[p] - 1.0f;
            bool outside = (s.x >= brx) | (s.x <= tlx) | (s.y >= tly) | (s.y <= bry);
            if (!outside) {
                float cx = floorf((s.x - tlx) / 2.0f * 8.0f);
                float cy = floorf((tly - s.y) / 2.0f * 8.0f);
                int cell = (int)(cx + cy * 8.0f);   // in [0,63] by strict bounds
                atomicAdd(&hist[p][cell], 1u);
            }
        }
    }
    __syncthreads();

    // ---- Phase 2: one wave per pedestrian ----------------------------------
    const int wave = tid >> 6;    // 0..3
    const int lane = tid & 63;    // 0..63
    const int ped  = ped0 + wave;

    // att2[j] = h . W_dec[:,j] + b_dec[j]   (lanes 0..31)
    if (lane < AD) {
        float a = b_dec[lane];
        #pragma unroll 8
        for (int k = 0; k < HD; ++k) a = fmaf(h_s[wave][k], W_dec[k * AD + lane], a);
        att2_s[wave][lane] = a;
    }
    __syncthreads();

    if (ped >= nped) return;   // no further block-wide syncs

    // att[c] = sum_j relu(cnt*W_enc[j] + b_enc[j] + att2[j]) * W_full[j] + b_full
    float cnt = (float)hist[wave][lane];
    float att = b_full[0];
    #pragma unroll 8
    for (int j = 0; j < AD; ++j) {
        float s = fmaf(cnt, W_enc[j], b_enc[j] + att2_s[wave][j]);
        att = fmaf(fmaxf(s, 0.f), W_full[j], att);
    }

    // softmax over the 64 cells (one wave)
    float m = att;
    #pragma unroll
    for (int off = 32; off; off >>= 1) m = fmaxf(m, __shfl_xor(m, off, 64));
    float e = __expf(att - m);
    float ssum = e;
    #pragma unroll
    for (int off = 32; off; off >>= 1) ssum += __shfl_xor(ssum, off, 64);
    float awe = cnt * e / ssum;
    #pragma unroll
    for (int off = 32; off; off >>= 1) awe += __shfl_xor(awe, off, 64);

    // gate = sigmoid(h . W_fbeta + b_fbeta)
    float gp = h_s[wave][lane] * W_fbeta[lane];
    #pragma unroll
    for (int off = 32; off; off >>= 1) gp += __shfl_xor(gp, off, 64);
    float gate = 1.f / (1.f + __expf(-(gp + b_fbeta[0])));
    float aweg = gate * awe;

    // x = [emb(4), gated awe] (computed redundantly on every lane)
    float ex = end_pos[ped * 2], ey = end_pos[ped * 2 + 1];
    float dx = disp_pos[ped * 2], dy = disp_pos[ped * 2 + 1];
    float x[5];
    #pragma unroll
    for (int eI = 0; eI < 4; ++eI)
        x[eI] = ex * W_emb[0 * 4 + eI] + ey * W_emb[1 * 4 + eI]
              + dx * W_emb[2 * 4 + eI] + dy * W_emb[3 * 4 + eI] + b_emb[eI];
    x[4] = aweg;

    // gates: lane computes columns {lane, 128+lane, 192+lane} (f-gate is dead)
    float acc_i = b_ih[lane]       + b_hh[lane];
    float acc_g = b_ih[128 + lane] + b_hh[128 + lane];
    float acc_o = b_ih[192 + lane] + b_hh[192 + lane];
    #pragma unroll
    for (int k = 0; k < 5; ++k) {
        acc_i = fmaf(x[k], W_ih[k * 256 + lane],       acc_i);
        acc_g = fmaf(x[k], W_ih[k * 256 + 128 + lane], acc_g);
        acc_o = fmaf(x[k], W_ih[k * 256 + 192 + lane], acc_o);
    }
    #pragma unroll 8
    for (int k = 0; k < HD; ++k) {
        float hk = h_s[wave][k];
        acc_i = fmaf(hk, W_hh[k * 256 + lane],       acc_i);
        acc_g = fmaf(hk, W_hh[k * 256 + 128 + lane], acc_g);
        acc_o = fmaf(hk, W_hh[k * 256 + 192 + lane], acc_o);
    }
    float sig_i = 1.f / (1.f + __expf(-acc_i));
    float sig_o = 1.f / (1.f + __expf(-acc_o));
    float cc = sig_i * tanhf(acc_g);
    out[ped * HD + lane] = sig_o * tanhf(cc);
}

extern "C" void kernel_launch(void* const* d_in, const int* in_sizes, int n_in,
                              void* d_out, int out_size, void* d_ws, size_t ws_size,
                              hipStream_t stream)
{
    const float* scene   = (const float*)d_in[0];
    const float* end_pos = (const float*)d_in[1];
    const float* disp    = (const float*)d_in[2];
    const float* h_in    = (const float*)d_in[3];
    const float* W_enc   = (const float*)d_in[4];
    const float* b_enc   = (const float*)d_in[5];
    const float* W_dec   = (const float*)d_in[6];
    const float* b_dec   = (const float*)d_in[7];
    const float* W_full  = (const float*)d_in[8];
    const float* b_full  = (const float*)d_in[9];
    const float* W_fbeta = (const float*)d_in[10];
    const float* b_fbeta = (const float*)d_in[11];
    const float* W_emb   = (const float*)d_in[12];
    const float* b_emb   = (const float*)d_in[13];
    const float* W_ih    = (const float*)d_in[14];
    const float* b_ih    = (const float*)d_in[15];
    const float* W_hh    = (const float*)d_in[16];
    const float* b_hh    = (const float*)d_in[17];
    float* out = (float*)d_out;

    const int nped = in_sizes[1] / 2;
    const int npts = in_sizes[0] / 2;
    const int blocks = (nped + PPB - 1) / PPB;

    hipLaunchKernelGGL(fused_ssfe_kernel, dim3(blocks), dim3(BLK), 0, stream,
        scene, end_pos, disp, h_in, W_enc, b_enc, W_dec, b_dec, W_full, b_full,
        W_fbeta, b_fbeta, W_emb, b_emb, W_ih, b_ih, W_hh, b_hh, out, nped, npts);
}

// Round 2
// 18.375 us; speedup vs baseline: 1.3809x; 1.3809x over previous
//
#include <hip/hip_runtime.h>

// StaticSceneFeatureExtractorGrid — fused single kernel, v2.
// 512 blocks x 512 threads (8 waves): 4 peds/block.
// Phase 1: per-block LDS histogram, float4 scene loads (2 pts/load).
// Phase 2: waves 0-3 att2 || waves 4-7 gate; softmax on waves 0-3;
//          LSTM K-loop split across wave pairs (p, p+4), LDS combine.

constexpr int CELLS = 64;   // 8x8 grid
constexpr int HD    = 64;   // H_DIM
constexpr int AD    = 32;   // ATT_DIM
constexpr int PPB   = 4;    // peds per block
constexpr int BLK   = 512;  // threads per block (8 waves)

__global__ __launch_bounds__(BLK) void fused_ssfe_kernel(
    const float* __restrict__ scene,     // [npts,2]
    const float* __restrict__ end_pos,   // [nped,2]
    const float* __restrict__ disp_pos,  // [nped,2]
    const float* __restrict__ h_in,      // [nped,64]
    const float* __restrict__ W_enc,     // [1,32]
    const float* __restrict__ b_enc,     // [32]
    const float* __restrict__ W_dec,     // [64,32]
    const float* __restrict__ b_dec,     // [32]
    const float* __restrict__ W_full,    // [32,1]
    const float* __restrict__ b_full,    // [1]
    const float* __restrict__ W_fbeta,   // [64,1]
    const float* __restrict__ b_fbeta,   // [1]
    const float* __restrict__ W_emb,     // [4,4]
    const float* __restrict__ b_emb,     // [4]
    const float* __restrict__ W_ih,      // [5,256]
    const float* __restrict__ b_ih,      // [256]
    const float* __restrict__ W_hh,      // [64,256]
    const float* __restrict__ b_hh,      // [256]
    float* __restrict__ out,             // [nped,64]
    int nped, int npts)
{
    __shared__ unsigned hist[PPB][CELLS];
    __shared__ float    h_s[PPB][HD];
    __shared__ float    att2_s[PPB][AD];
    __shared__ float    gate_s[PPB];
    __shared__ float    x_s[PPB][8];          // [0..3]=emb, [4]=gated awe
    __shared__ float    part[PPB][3][HD];     // half=1 LSTM partials

    const int tid  = threadIdx.x;
    const int ped0 = blockIdx.x * PPB;

    // zero histogram (PPB*CELLS == 256 <= BLK)
    if (tid < PPB * CELLS) ((unsigned*)hist)[tid] = 0u;

    // stage h into LDS: first 256 threads -> (ped p, element k)
    if (tid < PPB * HD) {
        int p = tid >> 6, k = tid & 63;
        int ped = ped0 + p;
        h_s[p][k] = (ped < nped) ? h_in[ped * HD + k] : 0.f;
    }

    // pedestrian boxes in registers (dummy box for tail peds -> always outside)
    float tlx[PPB], tly[PPB], brx[PPB], bry[PPB];
    #pragma unroll
    for (int p = 0; p < PPB; ++p) {
        float px, py;
        int ped = ped0 + p;
        if (ped < nped) { px = end_pos[ped * 2]; py = end_pos[ped * 2 + 1]; }
        else            { px = 1e30f;            py = 1e30f; }
        // bit-exact vs JAX: tlx=px-1, tly=py+1, brx=px+1, bry=py-1 (rounded)
        tlx[p] = px - 1.0f; tly[p] = py + 1.0f;
        brx[p] = px + 1.0f; bry[p] = py - 1.0f;
    }
    __syncthreads();

    // ---- Phase 1: histogram -------------------------------------------------
    auto test_point = [&](float sx, float sy) {
        #pragma unroll
        for (int p = 0; p < PPB; ++p) {
            bool outside = (sx >= brx[p]) | (sx <= tlx[p]) |
                           (sy >= tly[p]) | (sy <= bry[p]);
            if (!outside) {
                // (sx-tlx)/2*8 == (sx-tlx)*4 exactly (pow2 scalings)
                float cx = floorf((sx - tlx[p]) * 4.0f);
                float cy = floorf((tly[p] - sy) * 4.0f);
                int cell = (int)(cx + cy * 8.0f);   // in [0,63] by strict bounds
                atomicAdd(&hist[p][cell], 1u);
            }
        }
    };

    const float4* sc4 = reinterpret_cast<const float4*>(scene);
    const int n4 = npts >> 1;
    #pragma unroll 4
    for (int i = tid; i < n4; i += BLK) {
        float4 s = sc4[i];
        test_point(s.x, s.y);
        test_point(s.z, s.w);
    }
    if (npts & 1) {   // odd-tail guard (not hit at npts=8192)
        if (tid == 0) test_point(scene[(npts - 1) * 2], scene[(npts - 1) * 2 + 1]);
    }
    __syncthreads();

    // ---- Phase 2 ------------------------------------------------------------
    const int wave = tid >> 6;    // 0..7
    const int lane = tid & 63;
    const int p    = wave & 3;
    const int half = wave >> 2;   // 0 or 1
    const int ped  = ped0 + p;

    if (half == 0) {
        // waves 0-3: att2[j] = h . W_dec[:,j] + b_dec[j] (lanes 0..31)
        if (lane < AD && ped < nped) {
            float a = b_dec[lane];
            #pragma unroll 8
            for (int k = 0; k < HD; ++k) a = fmaf(h_s[p][k], W_dec[k * AD + lane], a);
            att2_s[p][lane] = a;
        }
    } else {
        // waves 4-7: gate = sigmoid(h . W_fbeta + b_fbeta)
        if (ped < nped) {
            float gp = h_s[p][lane] * W_fbeta[lane];
            #pragma unroll
            for (int off = 32; off; off >>= 1) gp += __shfl_xor(gp, off, 64);
            if (lane == 0) gate_s[p] = 1.f / (1.f + __expf(-(gp + b_fbeta[0])));
        }
    }
    __syncthreads();

    if (half == 0 && ped < nped) {
        // att[c] = sum_j relu(cnt*W_enc[j] + b_enc[j] + att2[j]) * W_full[j] + b_full
        float cnt = (float)hist[p][lane];
        float att = b_full[0];
        #pragma unroll 8
        for (int j = 0; j < AD; ++j) {
            float s = fmaf(cnt, W_enc[j], b_enc[j] + att2_s[p][j]);
            att = fmaf(fmaxf(s, 0.f), W_full[j], att);
        }
        // softmax over 64 cells (one wave)
        float m = att;
        #pragma unroll
        for (int off = 32; off; off >>= 1) m = fmaxf(m, __shfl_xor(m, off, 64));
        float e = __expf(att - m);
        float ssum = e;
        #pragma unroll
        for (int off = 32; off; off >>= 1) ssum += __shfl_xor(ssum, off, 64);
        float awe = cnt * e / ssum;
        #pragma unroll
        for (int off = 32; off; off >>= 1) awe += __shfl_xor(awe, off, 64);

        // x = [emb(4), gated awe]
        if (lane < 4) {
            float ex = end_pos[ped * 2], ey = end_pos[ped * 2 + 1];
            float dx = disp_pos[ped * 2], dy = disp_pos[ped * 2 + 1];
            x_s[p][lane] = ex * W_emb[0 * 4 + lane] + ey * W_emb[1 * 4 + lane]
                         + dx * W_emb[2 * 4 + lane] + dy * W_emb[3 * 4 + lane]
                         + b_emb[lane];
        }
        if (lane == 4) x_s[p][4] = gate_s[p] * awe;
    }
    __syncthreads();

    // ---- LSTM gates: K split across wave pairs (p, p+4) --------------------
    if (ped < nped) {
        float acc_i, acc_g, acc_o;
        if (half == 0) {
            acc_i = b_ih[lane]       + b_hh[lane];
            acc_g = b_ih[128 + lane] + b_hh[128 + lane];
            acc_o = b_ih[192 + lane] + b_hh[192 + lane];
            #pragma unroll
            for (int k = 0; k < 5; ++k) {
                float xk = x_s[p][k];
                acc_i = fmaf(xk, W_ih[k * 256 + lane],       acc_i);
                acc_g = fmaf(xk, W_ih[k * 256 + 128 + lane], acc_g);
                acc_o = fmaf(xk, W_ih[k * 256 + 192 + lane], acc_o);
            }
        } else {
            acc_i = 0.f; acc_g = 0.f; acc_o = 0.f;
        }
        const int k0 = half * 32;
        #pragma unroll 8
        for (int k = k0; k < k0 + 32; ++k) {
            float hk = h_s[p][k];
            acc_i = fmaf(hk, W_hh[k * 256 + lane],       acc_i);
            acc_g = fmaf(hk, W_hh[k * 256 + 128 + lane], acc_g);
            acc_o = fmaf(hk, W_hh[k * 256 + 192 + lane], acc_o);
        }
        if (half == 1) {
            part[p][0][lane] = acc_i;
            part[p][1][lane] = acc_g;
            part[p][2][lane] = acc_o;
        }
        __syncthreads();
        if (half == 0) {
            acc_i += part[p][0][lane];
            acc_g += part[p][1][lane];
            acc_o += part[p][2][lane];
            float sig_i = 1.f / (1.f + __expf(-acc_i));
            float sig_o = 1.f / (1.f + __expf(-acc_o));
            float cc = sig_i * tanhf(acc_g);
            out[ped * HD + lane] = sig_o * tanhf(cc);
        }
    } else {
        __syncthreads();   // keep barrier uniform across the block
    }
}

extern "C" void kernel_launch(void* const* d_in, const int* in_sizes, int n_in,
                              void* d_out, int out_size, void* d_ws, size_t ws_size,
                              hipStream_t stream)
{
    const float* scene   = (const float*)d_in[0];
    const float* end_pos = (const float*)d_in[1];
    const float* disp    = (const float*)d_in[2];
    const float* h_in    = (const float*)d_in[3];
    const float* W_enc   = (const float*)d_in[4];
    const float* b_enc   = (const float*)d_in[5];
    const float* W_dec   = (const float*)d_in[6];
    const float* b_dec   = (const float*)d_in[7];
    const float* W_full  = (const float*)d_in[8];
    const float* b_full  = (const float*)d_in[9];
    const float* W_fbeta = (const float*)d_in[10];
    const float* b_fbeta = (const float*)d_in[11];
    const float* W_emb   = (const float*)d_in[12];
    const float* b_emb   = (const float*)d_in[13];
    const float* W_ih    = (const float*)d_in[14];
    const float* b_ih    = (const float*)d_in[15];
    const float* W_hh    = (const float*)d_in[16];
    const float* b_hh    = (const float*)d_in[17];
    float* out = (float*)d_out;

    const int nped = in_sizes[1] / 2;
    const int npts = in_sizes[0] / 2;
    const int blocks = (nped + PPB - 1) / PPB;

    hipLaunchKernelGGL(fused_ssfe_kernel, dim3(blocks), dim3(BLK), 0, stream,
        scene, end_pos, disp, h_in, W_enc, b_enc, W_dec, b_dec, W_full, b_full,
        W_fbeta, b_fbeta, W_emb, b_emb, W_ih, b_ih, W_hh, b_hh, out, nped, npts);
}